// Round 10
// baseline (189.286 us; speedup 1.0000x reference)
//
#include <hip/hip_runtime.h>
#include <hip/hip_bf16.h>

// Types
typedef short  bf16x8 __attribute__((ext_vector_type(8)));
typedef float  f32x4  __attribute__((ext_vector_type(4)));
typedef unsigned short ushort_t;

#define BK 64

#define GLD_LDS16(gp, lp) __builtin_amdgcn_global_load_lds(                 \
    (const __attribute__((address_space(1))) void*)(gp),                    \
    (__attribute__((address_space(3))) void*)(lp), 16, 0, 0)

static __device__ inline short f2bf(float x) {
    unsigned u = __builtin_bit_cast(unsigned, x);
    u += 0x7fffu + ((u >> 16) & 1u);
    return (short)(u >> 16);
}

// ---------------------------------------------------------------------------
// Pre-pass: feats f32 -> bf16 row-major (16 MB), ~48 MB traffic
// ---------------------------------------------------------------------------
__global__ __launch_bounds__(256)
void convert_kernel(const float* __restrict__ in, ushort_t* __restrict__ out,
                    int n)
{
    int i = (blockIdx.x * blockDim.x + threadIdx.x) * 8;
    if (i < n) {
        f32x4 a = *(const f32x4*)(in + i);
        f32x4 b = *(const f32x4*)(in + i + 4);
        bf16x8 v;
        #pragma unroll
        for (int e = 0; e < 4; ++e) {
            v[e]     = f2bf(a[e]);
            v[e + 4] = f2bf(b[e]);
        }
        *(bf16x8*)(out + i) = v;
    }
}

// ---------------------------------------------------------------------------
// Gram kernel, m97-verbatim structure: FULL-SQUARE grid (nt*nt blocks,
// 4 queued/CU), 128x128 tile, SINGLE 32KB LDS buffer, 2-barrier K-loop.
// Inter-block overlap (3 resident blocks/CU) covers the vmcnt drain —
// the m114 mechanism. Strictly-upper tiles compute but skip epilogue.
// Staging uses global_load_lds w16 with pre-swizzled source (rule #21);
// LDS image identical to R2-R9 verified layout (0 bank conflicts).
// accbuf: [0]=S0 [1]=S1 [2]=ps [3]=pc
// ---------------------------------------------------------------------------
__global__ __launch_bounds__(256, 3)
void gram_m97_kernel(const ushort_t* __restrict__ fb,
                     const int* __restrict__ labels,
                     const int* __restrict__ biases,
                     float* __restrict__ accbuf,
                     int N, int D)
{
    __shared__ ushort_t As[128 * BK];   // 16 KB
    __shared__ ushort_t Bs[128 * BK];   // 16 KB
    __shared__ int lab_r[128], bia_r[128], lab_c[128], bia_c[128];

    int nt = N >> 7;
    int b  = blockIdx.x;
    int nwg = gridDim.x;
    if ((nwg & 7) == 0) b = (b & 7) * (nwg >> 3) + (b >> 3);  // XCD swizzle
    int r = b / nt, c = b % nt;        // consecutive b per XCD share A panel
    int rowbase = r * 128, colbase = c * 128;

    int tid = threadIdx.x;
    if (tid < 128) {
        lab_r[tid] = labels[rowbase + tid];
        bia_r[tid] = biases[rowbase + tid];
    } else {
        int u = tid - 128;
        lab_c[u] = labels[colbase + u];
        bia_c[u] = biases[colbase + u];
    }

    int lane = tid & 63;
    int wid  = tid >> 6;
    int wr   = wid >> 1;               // 2x2 wave grid, 64x64 each
    int wc   = wid & 1;
    int lrow = lane & 15;
    int kgrp = lane >> 4;

    f32x4 acc[4][4] = {};

    for (int k0 = 0; k0 < D; k0 += BK) {
        __syncthreads();               // prior compute done reading LDS
        // ---- stage A,B tiles (1024 x 16B chunks each) ----
        #pragma unroll
        for (int i = 0; i < 4; ++i) {
            int j   = i * 256 + tid;
            int row = j >> 3;
            int kc  = (j & 7) ^ (row & 7);    // pre-swizzled source slot
            const ushort_t* ga = fb + (size_t)(rowbase + row) * D + k0 + kc * 8;
            const ushort_t* gb = fb + (size_t)(colbase + row) * D + k0 + kc * 8;
            GLD_LDS16(ga, As + j * 8);
            GLD_LDS16(gb, Bs + j * 8);
        }
        __syncthreads();               // compiler drains vmcnt(0) here

        #pragma unroll
        for (int kk = 0; kk < 2; ++kk) {
            bf16x8 a[4], bb[4];
            #pragma unroll
            for (int m = 0; m < 4; ++m) {
                int rr = wr * 64 + m * 16 + lrow;
                int off = rr * 128 + ((kk * 64 + kgrp * 16) ^ ((rr & 7) << 4));
                a[m] = *(const bf16x8*)((const char*)As + off);
            }
            #pragma unroll
            for (int n = 0; n < 4; ++n) {
                int cc = wc * 64 + n * 16 + lrow;
                int off = cc * 128 + ((kk * 64 + kgrp * 16) ^ ((cc & 7) << 4));
                bb[n] = *(const bf16x8*)((const char*)Bs + off);
            }
            #pragma unroll
            for (int m = 0; m < 4; ++m)
                #pragma unroll
                for (int n = 0; n < 4; ++n)
                    acc[m][n] = __builtin_amdgcn_mfma_f32_16x16x32_bf16(
                        a[m], bb[n], acc[m][n], 0, 0, 0);
        }
    }

    if (r < c) return;                 // strictly-upper: no i>j pairs

    // ---- epilogue: clip + masks + reduce (verified R2-R9) ----
    // C/D layout: col = lane&15, row = (lane>>4)*4 + reg
    float s0 = 0.f, s1 = 0.f, ps = 0.f, pc = 0.f;
    #pragma unroll
    for (int m = 0; m < 4; ++m) {
        #pragma unroll
        for (int e = 0; e < 4; ++e) {
            int li = wr * 64 + m * 16 + kgrp * 4 + e;
            int gi = rowbase + li;
            int labi = lab_r[li];
            int bi   = bia_r[li];
            #pragma unroll
            for (int n = 0; n < 4; ++n) {
                int lj = wc * 64 + n * 16 + lrow;
                int gj = colbase + lj;
                if (gi > gj) {
                    float g = acc[m][n][e];
                    g = fminf(fmaxf(g, -1.f), 1.f);
                    int bj = bia_c[lj];
                    if (bi == bj) {
                        if (bi == 0) s0 += g; else s1 += g;
                    } else if (labi == lab_c[lj] && bi < bj) {
                        ps += 1.f + g;
                        pc += 1.f;
                    }
                }
            }
        }
    }
    #pragma unroll
    for (int off = 32; off > 0; off >>= 1) {
        s0 += __shfl_down(s0, off);
        s1 += __shfl_down(s1, off);
        ps += __shfl_down(ps, off);
        pc += __shfl_down(pc, off);
    }
    if (lane == 0) {
        atomicAdd(&accbuf[0], s0);
        atomicAdd(&accbuf[1], s1);
        atomicAdd(&accbuf[2], ps);
        atomicAdd(&accbuf[3], pc);
    }
}

// ---------------------------------------------------------------------------
// Cross-entropy + bias-class counts.  accbuf: [4]=CE sum [5]=n0 [6]=n1
// ---------------------------------------------------------------------------
__global__ __launch_bounds__(256)
void ce_count_kernel(const float* __restrict__ logits,
                     const int* __restrict__ labels,
                     const int* __restrict__ biases,
                     float* __restrict__ accbuf,
                     int N, int C)
{
    int i = blockIdx.x * blockDim.x + threadIdx.x;
    float loss = 0.f, c0 = 0.f, c1 = 0.f;
    if (i < N) {
        const float* row = logits + (size_t)i * C;
        float mx = -INFINITY;
        for (int k = 0; k < C; ++k) mx = fmaxf(mx, row[k]);
        float s = 0.f;
        for (int k = 0; k < C; ++k) s += expf(row[k] - mx);
        loss = mx + logf(s) - row[labels[i]];
        if (biases[i] == 0) c0 = 1.f; else c1 = 1.f;
    }
    #pragma unroll
    for (int off = 32; off > 0; off >>= 1) {
        loss += __shfl_down(loss, off);
        c0   += __shfl_down(c0, off);
        c1   += __shfl_down(c1, off);
    }
    if ((threadIdx.x & 63) == 0) {
        atomicAdd(&accbuf[4], loss);
        atomicAdd(&accbuf[5], c0);
        atomicAdd(&accbuf[6], c1);
    }
}

// ---------------------------------------------------------------------------
// Finalize
// ---------------------------------------------------------------------------
__global__ void finalize_kernel(const float* __restrict__ accbuf,
                                float* __restrict__ out, int N)
{
    float S0 = accbuf[0], S1 = accbuf[1], ps = accbuf[2], pc = accbuf[3];
    float ce = accbuf[4], n0 = accbuf[5], n1 = accbuf[6];
    float Mo = 0.5f * (n0 * (n0 - 1.f) + n1 * (n1 - 1.f));
    float Ro = (Mo > 0.f) ? (fabsf(S0) + fabsf(S1)) / Mo : 0.f;
    float Rp = (pc > 0.f) ? 1.f + (-0.5f * ps) / pc : 0.f;
    out[0] = ce / (float)N;
    out[1] = Ro + Rp;   // ALPHA=BETA=1
}

extern "C" void kernel_launch(void* const* d_in, const int* in_sizes, int n_in,
                              void* d_out, int out_size, void* d_ws, size_t ws_size,
                              hipStream_t stream)
{
    const float* logits = (const float*)d_in[0];
    const int*   labels = (const int*)d_in[1];
    const int*   biases = (const int*)d_in[2];
    const float* feats  = (const float*)d_in[3];

    int N = in_sizes[1];              // 4096
    int C = in_sizes[0] / N;          // 10
    int D = in_sizes[3] / N;          // 2048

    float* accbuf = (float*)d_ws;
    hipMemsetAsync(accbuf, 0, 8 * sizeof(float), stream);

    ushort_t* fb = (ushort_t*)((char*)d_ws + 256);
    int nconv = N * D;
    convert_kernel<<<(nconv / 8 + 255) / 256, 256, 0, stream>>>(feats, fb,
                                                                nconv);

    int nt = N >> 7;                  // 32
    gram_m97_kernel<<<nt * nt, 256, 0, stream>>>(fb, labels, biases, accbuf,
                                                 N, D);
    ce_count_kernel<<<(N + 255) / 256, 256, 0, stream>>>(logits, labels, biases,
                                                         accbuf, N, C);
    finalize_kernel<<<1, 1, 0, stream>>>(accbuf, (float*)d_out, N);
}

// Round 11
// 172.400 us; speedup vs baseline: 1.0979x; 1.0979x over previous
//
#include <hip/hip_runtime.h>
#include <hip/hip_bf16.h>

// Types
typedef float  f32x4  __attribute__((ext_vector_type(4)));
typedef unsigned int  uint4v __attribute__((ext_vector_type(4)));
typedef unsigned long u64x2  __attribute__((ext_vector_type(2)));
typedef short  bf16x8 __attribute__((ext_vector_type(8)));
typedef unsigned short ushort_t;

#define GLD_LDS16(gp, lp) __builtin_amdgcn_global_load_lds(                 \
    (const __attribute__((address_space(1))) void*)(gp),                    \
    (__attribute__((address_space(3))) void*)(lp), 16, 0, 0)

static __device__ inline short f2bf(float x) {
    unsigned u = __builtin_bit_cast(unsigned, x);
    u += 0x7fffu + ((u >> 16) & 1u);
    return (short)(u >> 16);
}

// ---------------------------------------------------------------------------
// Pre-pass: feats f32 -> fp8 e4m3, PAIR-INTERLEAVED row-major.
// Per row: P128-blocks (128 K-values = 128B), 8 units of 16B each.
// Unit g (pairIdx=g>>2, kgrp=g&3) holds row k-bytes
//   [P*128 + pairIdx*64 + kgrp*8 .. +8)  followed by  [same + 32 .. +8).
// One ds_read_b128 of a unit yields TWO K=32 MFMA fragments.
// ---------------------------------------------------------------------------
__global__ __launch_bounds__(256)
void convert_pair8_kernel(const float* __restrict__ in,
                          unsigned char* __restrict__ out,
                          int N, int D)
{
    int uid = blockIdx.x * blockDim.x + threadIdx.x;   // 16B unit id
    int nP = D >> 7;
    int nu = N * nP * 8;
    if (uid >= nu) return;
    int g   = uid & 7;
    int q   = uid >> 3;
    int P   = q % nP;
    int row = q / nP;
    int kb  = P * 128 + ((g >> 2) << 6) + ((g & 3) << 3);
    const float* s = in + (size_t)row * D + kb;
    f32x4 a0 = *(const f32x4*)s;
    f32x4 a1 = *(const f32x4*)(s + 4);
    f32x4 b0 = *(const f32x4*)(s + 32);
    f32x4 b1 = *(const f32x4*)(s + 36);
    unsigned w0 = __builtin_amdgcn_cvt_pk_fp8_f32(a0[0], a0[1], 0, 0);
    w0 = __builtin_amdgcn_cvt_pk_fp8_f32(a0[2], a0[3], w0, 1);
    unsigned w1 = __builtin_amdgcn_cvt_pk_fp8_f32(a1[0], a1[1], 0, 0);
    w1 = __builtin_amdgcn_cvt_pk_fp8_f32(a1[2], a1[3], w1, 1);
    unsigned w2 = __builtin_amdgcn_cvt_pk_fp8_f32(b0[0], b0[1], 0, 0);
    w2 = __builtin_amdgcn_cvt_pk_fp8_f32(b0[2], b0[3], w2, 1);
    unsigned w3 = __builtin_amdgcn_cvt_pk_fp8_f32(b1[0], b1[1], 0, 0);
    w3 = __builtin_amdgcn_cvt_pk_fp8_f32(b1[2], b1[3], w3, 1);
    uint4v v = {w0, w1, w2, w3};
    *(uint4v*)(out + (size_t)uid * 16) = v;
}

// ---------------------------------------------------------------------------
// Gram kernel: m97 structure (R10, proven 6.4 TB/s delivery) x fp8 payload
// (R8/R9, absmax 0.0). Full-square grid nt*nt (4 queued/CU), 128x128 tile,
// SINGLE 32KB LDS buffer, 2-barrier K-loop, BK=128 fp8 (16 iterations).
// Staging: 8-lane groups fetch one full 128B line (unit-permuted in-line,
// rule #21); LDS dest linear; reads XOR (row&7) over 8 units -> <=2-way
// banks (free). 16 ds_read_b128 + 64 MFMA per iteration.
// accbuf: [0]=S0 [1]=S1 [2]=ps [3]=pc
// ---------------------------------------------------------------------------
__global__ __launch_bounds__(256, 3)
void gram8_m97_kernel(const unsigned char* __restrict__ fb,
                      const int* __restrict__ labels,
                      const int* __restrict__ biases,
                      float* __restrict__ accbuf,
                      int N, int D)
{
    __shared__ unsigned char As[128 * 128];   // 16 KB
    __shared__ unsigned char Bs[128 * 128];   // 16 KB
    __shared__ int lab_r[128], bia_r[128], lab_c[128], bia_c[128];

    int nt = N >> 7;
    int b  = blockIdx.x;
    int nwg = gridDim.x;
    if ((nwg & 7) == 0) b = (b & 7) * (nwg >> 3) + (b >> 3);  // XCD swizzle
    int r = b / nt, c = b % nt;        // consecutive b per XCD share A panel
    int rowbase = r * 128, colbase = c * 128;

    int tid = threadIdx.x;
    if (tid < 128) {
        lab_r[tid] = labels[rowbase + tid];
        bia_r[tid] = biases[rowbase + tid];
    } else {
        int u = tid - 128;
        lab_c[u] = labels[colbase + u];
        bia_c[u] = biases[colbase + u];
    }

    int lane = tid & 63;
    int wid  = tid >> 6;
    int wr   = wid >> 1;               // 2x2 wave grid, 64x64 each
    int wc   = wid & 1;
    int lrow = lane & 15;
    int kgrp = lane >> 4;

    int nP = D >> 7;                   // 16 K-steps
    f32x4 acc[4][4] = {};

    for (int P = 0; P < nP; ++P) {
        __syncthreads();               // prior compute done reading LDS
        // ---- stage A,B tiles: 1024 x 16B units each ----
        #pragma unroll
        for (int i = 0; i < 4; ++i) {
            int j   = i * 256 + tid;   // 0..1023
            int row = j >> 3;
            int g   = (j & 7) ^ (row & 7);    // pre-swizzled unit in line
            const unsigned char* ga =
                fb + ((size_t)(rowbase + row) * nP + P) * 128 + g * 16;
            const unsigned char* gb =
                fb + ((size_t)(colbase + row) * nP + P) * 128 + g * 16;
            GLD_LDS16(ga, As + j * 16);
            GLD_LDS16(gb, Bs + j * 16);
        }
        __syncthreads();               // compiler drains vmcnt(0) here

        #pragma unroll
        for (int pi = 0; pi < 2; ++pi) {
            u64x2 a2[4], b2[4];
            #pragma unroll
            for (int m = 0; m < 4; ++m) {
                int rr = wr * 64 + m * 16 + lrow;
                int off = rr * 128 + (((pi * 4 + kgrp) ^ (rr & 7)) << 4);
                a2[m] = *(const u64x2*)(As + off);
            }
            #pragma unroll
            for (int n = 0; n < 4; ++n) {
                int cc = wc * 64 + n * 16 + lrow;
                int off = cc * 128 + (((pi * 4 + kgrp) ^ (cc & 7)) << 4);
                b2[n] = *(const u64x2*)(Bs + off);
            }
            #pragma unroll
            for (int m = 0; m < 4; ++m)
                #pragma unroll
                for (int n = 0; n < 4; ++n) {
                    acc[m][n] = __builtin_amdgcn_mfma_f32_16x16x32_fp8_fp8(
                        (long)a2[m][0], (long)b2[n][0], acc[m][n], 0, 0, 0);
                    acc[m][n] = __builtin_amdgcn_mfma_f32_16x16x32_fp8_fp8(
                        (long)a2[m][1], (long)b2[n][1], acc[m][n], 0, 0, 0);
                }
        }
    }

    if (r < c) return;                 // strictly-upper: no i>j pairs

    // ---- epilogue: clip + masks + reduce (verified R2-R10) ----
    // C/D layout: col = lane&15, row = (lane>>4)*4 + reg
    float s0 = 0.f, s1 = 0.f, ps = 0.f, pc = 0.f;
    #pragma unroll
    for (int m = 0; m < 4; ++m) {
        #pragma unroll
        for (int e = 0; e < 4; ++e) {
            int li = wr * 64 + m * 16 + kgrp * 4 + e;
            int gi = rowbase + li;
            int labi = lab_r[li];
            int bi   = bia_r[li];
            #pragma unroll
            for (int n = 0; n < 4; ++n) {
                int lj = wc * 64 + n * 16 + lrow;
                int gj = colbase + lj;
                if (gi > gj) {
                    float g = acc[m][n][e];
                    g = fminf(fmaxf(g, -1.f), 1.f);
                    int bj = bia_c[lj];
                    if (bi == bj) {
                        if (bi == 0) s0 += g; else s1 += g;
                    } else if (labi == lab_c[lj] && bi < bj) {
                        ps += 1.f + g;
                        pc += 1.f;
                    }
                }
            }
        }
    }
    #pragma unroll
    for (int off = 32; off > 0; off >>= 1) {
        s0 += __shfl_down(s0, off);
        s1 += __shfl_down(s1, off);
        ps += __shfl_down(ps, off);
        pc += __shfl_down(pc, off);
    }
    if (lane == 0) {
        atomicAdd(&accbuf[0], s0);
        atomicAdd(&accbuf[1], s1);
        atomicAdd(&accbuf[2], ps);
        atomicAdd(&accbuf[3], pc);
    }
}

// ---------------------------------------------------------------------------
// Fallback (ws too small): fused f32->bf16 staging (R2, verified)
// ---------------------------------------------------------------------------
__global__ __launch_bounds__(256, 2)
void gram_fused_kernel(const float* __restrict__ feats,
                       const int* __restrict__ labels,
                       const int* __restrict__ biases,
                       float* __restrict__ accbuf,
                       int N, int D)
{
    __shared__ ushort_t As[128 * 64];
    __shared__ ushort_t Bs[128 * 64];
    __shared__ int lab_r[128], bia_r[128], lab_c[128], bia_c[128];

    int t = blockIdx.x;
    int r = (int)((sqrtf(8.0f * (float)t + 1.0f) - 1.0f) * 0.5f);
    while ((r + 1) * (r + 2) / 2 <= t) ++r;
    while (r * (r + 1) / 2 > t) --r;
    int c = t - r * (r + 1) / 2;
    int rowbase = r * 128, colbase = c * 128;

    int tid = threadIdx.x;
    if (tid < 128) {
        lab_r[tid] = labels[rowbase + tid];
        bia_r[tid] = biases[rowbase + tid];
    } else {
        int u = tid - 128;
        lab_c[u] = labels[colbase + u];
        bia_c[u] = biases[colbase + u];
    }

    int lane = tid & 63;
    int wid  = tid >> 6;
    int wr   = wid >> 1;
    int wc   = wid & 1;
    int lrow = lane & 15;
    int kgrp = lane >> 4;

    f32x4 acc[4][4] = {};

    for (int k0 = 0; k0 < D; k0 += 64) {
        __syncthreads();
        #pragma unroll
        for (int it = 0; it < 4; ++it) {
            int wlin = tid + it * 256;
            int row  = wlin >> 3;
            int kc   = wlin & 7;
            const float* ga = feats + (size_t)(rowbase + row) * D + k0 + kc * 8;
            const float* gb = feats + (size_t)(colbase + row) * D + k0 + kc * 8;
            f32x4 a0 = *(const f32x4*)ga;
            f32x4 a1 = *(const f32x4*)(ga + 4);
            f32x4 b0 = *(const f32x4*)gb;
            f32x4 b1 = *(const f32x4*)(gb + 4);
            bf16x8 av, bv;
            #pragma unroll
            for (int e = 0; e < 4; ++e) {
                av[e]     = f2bf(a0[e]);
                av[e + 4] = f2bf(a1[e]);
                bv[e]     = f2bf(b0[e]);
                bv[e + 4] = f2bf(b1[e]);
            }
            int boff = row * 128 + ((kc * 16) ^ ((row & 7) << 4));
            *(bf16x8*)((char*)As + boff) = av;
            *(bf16x8*)((char*)Bs + boff) = bv;
        }
        __syncthreads();

        #pragma unroll
        for (int kk = 0; kk < 2; ++kk) {
            bf16x8 a[4], bb[4];
            #pragma unroll
            for (int m = 0; m < 4; ++m) {
                int rr = wr * 64 + m * 16 + lrow;
                int off = rr * 128 + ((kk * 64 + kgrp * 16) ^ ((rr & 7) << 4));
                a[m] = *(const bf16x8*)((const char*)As + off);
            }
            #pragma unroll
            for (int n = 0; n < 4; ++n) {
                int cc = wc * 64 + n * 16 + lrow;
                int off = cc * 128 + ((kk * 64 + kgrp * 16) ^ ((cc & 7) << 4));
                bb[n] = *(const bf16x8*)((const char*)Bs + off);
            }
            #pragma unroll
            for (int m = 0; m < 4; ++m)
                #pragma unroll
                for (int n = 0; n < 4; ++n)
                    acc[m][n] = __builtin_amdgcn_mfma_f32_16x16x32_bf16(
                        a[m], bb[n], acc[m][n], 0, 0, 0);
        }
    }

    float s0 = 0.f, s1 = 0.f, ps = 0.f, pc = 0.f;
    #pragma unroll
    for (int m = 0; m < 4; ++m) {
        #pragma unroll
        for (int e = 0; e < 4; ++e) {
            int li = wr * 64 + m * 16 + kgrp * 4 + e;
            int gi = rowbase + li;
            int labi = lab_r[li];
            int bi   = bia_r[li];
            #pragma unroll
            for (int n = 0; n < 4; ++n) {
                int lj = wc * 64 + n * 16 + lrow;
                int gj = colbase + lj;
                if (gi > gj) {
                    float g = acc[m][n][e];
                    g = fminf(fmaxf(g, -1.f), 1.f);
                    int bj = bia_c[lj];
                    if (bi == bj) {
                        if (bi == 0) s0 += g; else s1 += g;
                    } else if (labi == lab_c[lj] && bi < bj) {
                        ps += 1.f + g;
                        pc += 1.f;
                    }
                }
            }
        }
    }
    #pragma unroll
    for (int off = 32; off > 0; off >>= 1) {
        s0 += __shfl_down(s0, off);
        s1 += __shfl_down(s1, off);
        ps += __shfl_down(ps, off);
        pc += __shfl_down(pc, off);
    }
    if (lane == 0) {
        atomicAdd(&accbuf[0], s0);
        atomicAdd(&accbuf[1], s1);
        atomicAdd(&accbuf[2], ps);
        atomicAdd(&accbuf[3], pc);
    }
}

// ---------------------------------------------------------------------------
// Cross-entropy + bias-class counts.  accbuf: [4]=CE sum [5]=n0 [6]=n1
// ---------------------------------------------------------------------------
__global__ __launch_bounds__(256)
void ce_count_kernel(const float* __restrict__ logits,
                     const int* __restrict__ labels,
                     const int* __restrict__ biases,
                     float* __restrict__ accbuf,
                     int N, int C)
{
    int i = blockIdx.x * blockDim.x + threadIdx.x;
    float loss = 0.f, c0 = 0.f, c1 = 0.f;
    if (i < N) {
        const float* row = logits + (size_t)i * C;
        float mx = -INFINITY;
        for (int k = 0; k < C; ++k) mx = fmaxf(mx, row[k]);
        float s = 0.f;
        for (int k = 0; k < C; ++k) s += expf(row[k] - mx);
        loss = mx + logf(s) - row[labels[i]];
        if (biases[i] == 0) c0 = 1.f; else c1 = 1.f;
    }
    #pragma unroll
    for (int off = 32; off > 0; off >>= 1) {
        loss += __shfl_down(loss, off);
        c0   += __shfl_down(c0, off);
        c1   += __shfl_down(c1, off);
    }
    if ((threadIdx.x & 63) == 0) {
        atomicAdd(&accbuf[4], loss);
        atomicAdd(&accbuf[5], c0);
        atomicAdd(&accbuf[6], c1);
    }
}

// ---------------------------------------------------------------------------
// Finalize
// ---------------------------------------------------------------------------
__global__ void finalize_kernel(const float* __restrict__ accbuf,
                                float* __restrict__ out, int N)
{
    float S0 = accbuf[0], S1 = accbuf[1], ps = accbuf[2], pc = accbuf[3];
    float ce = accbuf[4], n0 = accbuf[5], n1 = accbuf[6];
    float Mo = 0.5f * (n0 * (n0 - 1.f) + n1 * (n1 - 1.f));
    float Ro = (Mo > 0.f) ? (fabsf(S0) + fabsf(S1)) / Mo : 0.f;
    float Rp = (pc > 0.f) ? 1.f + (-0.5f * ps) / pc : 0.f;
    out[0] = ce / (float)N;
    out[1] = Ro + Rp;   // ALPHA=BETA=1
}

extern "C" void kernel_launch(void* const* d_in, const int* in_sizes, int n_in,
                              void* d_out, int out_size, void* d_ws, size_t ws_size,
                              hipStream_t stream)
{
    const float* logits = (const float*)d_in[0];
    const int*   labels = (const int*)d_in[1];
    const int*   biases = (const int*)d_in[2];
    const float* feats  = (const float*)d_in[3];

    int N = in_sizes[1];              // 4096
    int C = in_sizes[0] / N;          // 10
    int D = in_sizes[3] / N;          // 2048

    float* accbuf = (float*)d_ws;
    hipMemsetAsync(accbuf, 0, 8 * sizeof(float), stream);

    size_t need = 256 + (size_t)N * D;            // 8 MB fp8 + hdr
    if (ws_size >= need && (D & 127) == 0 && (N & 127) == 0) {
        unsigned char* fb = (unsigned char*)d_ws + 256;
        int nu = N * (D >> 7) * 8;
        convert_pair8_kernel<<<(nu + 255) / 256, 256, 0, stream>>>(feats, fb,
                                                                   N, D);
        int nt = N >> 7;
        gram8_m97_kernel<<<nt * nt, 256, 0, stream>>>(fb, labels, biases,
                                                      accbuf, N, D);
    } else {
        int nt = N / 128;
        int T  = nt * (nt + 1) / 2;
        gram_fused_kernel<<<T, 256, 0, stream>>>(feats, labels, biases, accbuf,
                                                 N, D);
    }
    ce_count_kernel<<<(N + 255) / 256, 256, 0, stream>>>(logits, labels, biases,
                                                         accbuf, N, C);
    finalize_kernel<<<1, 1, 0, stream>>>(accbuf, (float*)d_out, N);
}

// Round 12
// 147.391 us; speedup vs baseline: 1.2842x; 1.1697x over previous
//
#include <hip/hip_runtime.h>
#include <hip/hip_bf16.h>

// Types
typedef short  bf16x8 __attribute__((ext_vector_type(8)));
typedef float  f32x4  __attribute__((ext_vector_type(4)));
typedef unsigned short ushort_t;

#define GLD_LDS16(gp, lp) __builtin_amdgcn_global_load_lds(                 \
    (const __attribute__((address_space(1))) void*)(gp),                    \
    (__attribute__((address_space(3))) void*)(lp), 16, 0, 0)

static __device__ inline short f2bf(float x) {
    unsigned u = __builtin_bit_cast(unsigned, x);
    u += 0x7fffu + ((u >> 16) & 1u);
    return (short)(u >> 16);
}

// ---------------------------------------------------------------------------
// Pre-pass: feats f32 -> bf16 row-major (16 MB)
// ---------------------------------------------------------------------------
__global__ __launch_bounds__(256)
void convert_kernel(const float* __restrict__ in, ushort_t* __restrict__ out,
                    int n)
{
    int i = (blockIdx.x * blockDim.x + threadIdx.x) * 8;
    if (i < n) {
        f32x4 a = *(const f32x4*)(in + i);
        f32x4 b = *(const f32x4*)(in + i + 4);
        bf16x8 v;
        #pragma unroll
        for (int e = 0; e < 4; ++e) {
            v[e]     = f2bf(a[e]);
            v[e + 4] = f2bf(b[e]);
        }
        *(bf16x8*)(out + i) = v;
    }
}

// ---------------------------------------------------------------------------
// Gram kernel: m201-style 8-phase 256x256 tile, 512 threads (8 waves, 2Mx4N),
// BK=64, 2 K-tiles/iteration, double-buffered 128KB LDS, counted vmcnt(6)
// at phases 4/8 ONLY (loads stay in flight across barriers - T3+T4), raw
// s_barrier + lgkmcnt(0) + setprio around MFMA clusters (T5).
// Full-square 16x16=256 blocks (1/CU); XCD swizzle: XCD x owns tile-rows
// {2x,2x+1} (A-panel 2MB L2-resident). Upper-tri blocks skip epilogue.
// LDS image = XOR-swizzled via pre-swizzled global source (rule #21,
// verified 0 conflicts R3-R11).
// accbuf: [0]=S0 [1]=S1 [2]=ps [3]=pc
// ---------------------------------------------------------------------------
__global__ __launch_bounds__(512, 2)
void gram_8phase_kernel(const ushort_t* __restrict__ fb,
                        const int* __restrict__ labels,
                        const int* __restrict__ biases,
                        float* __restrict__ accbuf,
                        int N, int D)
{
    __shared__ ushort_t As[2][2][128][64];   // [dbuf][half][row][k] 64KB
    __shared__ ushort_t Bs[2][2][128][64];   // 64KB
    __shared__ int lab_r[256], bia_r[256], lab_c[256], bia_c[256];

    int nt = N >> 8;                   // 16
    int b  = blockIdx.x;
    int nwg = gridDim.x;
    if ((nwg & 7) == 0) b = (b & 7) * (nwg >> 3) + (b >> 3);
    int r = b / nt, c = b % nt;
    int rowbase = r * 256, colbase = c * 256;

    int tid = threadIdx.x;
    if (tid < 256) {
        lab_r[tid] = labels[rowbase + tid];
        bia_r[tid] = biases[rowbase + tid];
    } else {
        int u = tid - 256;
        lab_c[u] = labels[colbase + u];
        bia_c[u] = biases[colbase + u];
    }

    int lane = tid & 63;
    int wid  = tid >> 6;               // 8 waves
    int wr   = wid >> 2;               // 0..1  (128 rows each)
    int wc   = wid & 3;                // 0..3  (64 cols each)
    int lrow = lane & 15;
    int kgrp = lane >> 4;

    // stage one half-tile (128 rows x 64 K bf16 = 16KB): 1024 chunks of 16B,
    // 2 per thread; source chunk pre-swizzled so LDS image is XOR-swizzled.
    auto STAGE_A = [&](int buf, int h, int kt) {
        #pragma unroll
        for (int ii = 0; ii < 2; ++ii) {
            int j   = ii * 512 + tid;
            int row = j >> 3;
            int kc  = (j & 7) ^ (row & 7);
            const ushort_t* g =
                fb + (size_t)(rowbase + h * 128 + row) * D + kt * 64 + kc * 8;
            GLD_LDS16(g, &As[buf][h][0][0] + j * 8);
        }
    };
    auto STAGE_B = [&](int buf, int h, int kt) {
        #pragma unroll
        for (int ii = 0; ii < 2; ++ii) {
            int j   = ii * 512 + tid;
            int row = j >> 3;
            int kc  = (j & 7) ^ (row & 7);
            const ushort_t* g =
                fb + (size_t)(colbase + h * 128 + row) * D + kt * 64 + kc * 8;
            GLD_LDS16(g, &Bs[buf][h][0][0] + j * 8);
        }
    };

    f32x4 acc[8][4] = {};
    int nIter = D >> 7;                // 16 iterations, 2 K-tiles each

    // ---- prologue: stage buf0 (K-tiles 0,1), drain once ----
    STAGE_A(0, 0, 0); STAGE_A(0, 1, 0); STAGE_B(0, 0, 0); STAGE_B(0, 1, 0);
    STAGE_A(0, 0, 1); STAGE_A(0, 1, 1); STAGE_B(0, 0, 1); STAGE_B(0, 1, 1);
    asm volatile("s_waitcnt vmcnt(0)" ::: "memory");
    __builtin_amdgcn_s_barrier();

    int hb = wc >> 1;                  // B half this wave reads
    int lcb = (wc & 1) * 64;           // B local col base within half

    for (int i = 0; i < nIter; ++i) {
        int cur = i & 1;
        int stg = (i + 1 < nIter);
        bf16x8 breg[4][2];

        #pragma unroll
        for (int half = 0; half < 2; ++half) {      // K-tile 2i+half
            int ktn = 2 * (i + 1) + half;           // staged K-tile
            #pragma unroll
            for (int q = 0; q < 4; ++q) {           // phase
                // ---- ds_read subtile ----
                if (q == 0) {
                    #pragma unroll
                    for (int n = 0; n < 4; ++n)
                        #pragma unroll
                        for (int ks = 0; ks < 2; ++ks) {
                            int lc = lcb + n * 16 + lrow;
                            breg[n][ks] = *(const bf16x8*)(
                                &Bs[cur][hb][lc][0] +
                                (((ks * 4 + kgrp) ^ (lc & 7)) << 3));
                        }
                }
                bf16x8 areg[2][2];
                #pragma unroll
                for (int mm = 0; mm < 2; ++mm)
                    #pragma unroll
                    for (int ks = 0; ks < 2; ++ks) {
                        int lr = (q * 2 + mm) * 16 + lrow;
                        areg[mm][ks] = *(const bf16x8*)(
                            &As[cur][wr][lr][0] +
                            (((ks * 4 + kgrp) ^ (lr & 7)) << 3));
                    }
                // ---- stage one half-tile of next iteration ----
                if (stg) {
                    if (q == 0)      STAGE_A(cur ^ 1, 0, ktn);
                    else if (q == 1) STAGE_A(cur ^ 1, 1, ktn);
                    else if (q == 2) STAGE_B(cur ^ 1, 0, ktn);
                    else             STAGE_B(cur ^ 1, 1, ktn);
                }
                // ---- counted vmcnt once per K-tile (phases 4 and 8) ----
                if (q == 3)
                    asm volatile("s_waitcnt vmcnt(6)" ::: "memory");
                __builtin_amdgcn_s_barrier();
                asm volatile("s_waitcnt lgkmcnt(0)" ::: "memory");
                __builtin_amdgcn_s_setprio(1);
                #pragma unroll
                for (int mm = 0; mm < 2; ++mm)
                    #pragma unroll
                    for (int n = 0; n < 4; ++n)
                        #pragma unroll
                        for (int ks = 0; ks < 2; ++ks)
                            acc[q * 2 + mm][n] =
                                __builtin_amdgcn_mfma_f32_16x16x32_bf16(
                                    areg[mm][ks], breg[n][ks],
                                    acc[q * 2 + mm][n], 0, 0, 0);
                __builtin_amdgcn_s_setprio(0);
                __builtin_amdgcn_s_barrier();
            }
        }
    }

    if (r < c) return;                 // strictly-upper: no i>j pairs

    // ---- epilogue: clip + masks + reduce (verified R2-R11) ----
    // C/D layout: col = lane&15, row = (lane>>4)*4 + reg
    float s0 = 0.f, s1 = 0.f, ps = 0.f, pc = 0.f;
    #pragma unroll
    for (int m = 0; m < 8; ++m) {
        #pragma unroll
        for (int e = 0; e < 4; ++e) {
            int li = wr * 128 + m * 16 + kgrp * 4 + e;
            int gi = rowbase + li;
            int labi = lab_r[li];
            int bi   = bia_r[li];
            #pragma unroll
            for (int n = 0; n < 4; ++n) {
                int lj = wc * 64 + n * 16 + lrow;
                int gj = colbase + lj;
                if (gi > gj) {
                    float g = acc[m][n][e];
                    g = fminf(fmaxf(g, -1.f), 1.f);
                    int bj = bia_c[lj];
                    if (bi == bj) {
                        if (bi == 0) s0 += g; else s1 += g;
                    } else if (labi == lab_c[lj] && bi < bj) {
                        ps += 1.f + g;
                        pc += 1.f;
                    }
                }
            }
        }
    }
    #pragma unroll
    for (int off = 32; off > 0; off >>= 1) {
        s0 += __shfl_down(s0, off);
        s1 += __shfl_down(s1, off);
        ps += __shfl_down(ps, off);
        pc += __shfl_down(pc, off);
    }
    if (lane == 0) {
        atomicAdd(&accbuf[0], s0);
        atomicAdd(&accbuf[1], s1);
        atomicAdd(&accbuf[2], ps);
        atomicAdd(&accbuf[3], pc);
    }
}

// ---------------------------------------------------------------------------
// Fallback (non-4096 shapes / small ws): fused f32->bf16 staging (R2, proven)
// ---------------------------------------------------------------------------
__global__ __launch_bounds__(256, 2)
void gram_fused_kernel(const float* __restrict__ feats,
                       const int* __restrict__ labels,
                       const int* __restrict__ biases,
                       float* __restrict__ accbuf,
                       int N, int D)
{
    __shared__ ushort_t As[128 * 64];
    __shared__ ushort_t Bs[128 * 64];
    __shared__ int lab_r[128], bia_r[128], lab_c[128], bia_c[128];

    int t = blockIdx.x;
    int r = (int)((sqrtf(8.0f * (float)t + 1.0f) - 1.0f) * 0.5f);
    while ((r + 1) * (r + 2) / 2 <= t) ++r;
    while (r * (r + 1) / 2 > t) --r;
    int c = t - r * (r + 1) / 2;
    int rowbase = r * 128, colbase = c * 128;

    int tid = threadIdx.x;
    if (tid < 128) {
        lab_r[tid] = labels[rowbase + tid];
        bia_r[tid] = biases[rowbase + tid];
    } else {
        int u = tid - 128;
        lab_c[u] = labels[colbase + u];
        bia_c[u] = biases[colbase + u];
    }

    int lane = tid & 63;
    int wid  = tid >> 6;
    int wr   = wid >> 1;
    int wc   = wid & 1;
    int lrow = lane & 15;
    int kgrp = lane >> 4;

    f32x4 acc[4][4] = {};

    for (int k0 = 0; k0 < D; k0 += 64) {
        __syncthreads();
        #pragma unroll
        for (int it = 0; it < 4; ++it) {
            int wlin = tid + it * 256;
            int row  = wlin >> 3;
            int kc   = wlin & 7;
            const float* ga = feats + (size_t)(rowbase + row) * D + k0 + kc * 8;
            const float* gb = feats + (size_t)(colbase + row) * D + k0 + kc * 8;
            f32x4 a0 = *(const f32x4*)ga;
            f32x4 a1 = *(const f32x4*)(ga + 4);
            f32x4 b0 = *(const f32x4*)gb;
            f32x4 b1 = *(const f32x4*)(gb + 4);
            bf16x8 av, bv;
            #pragma unroll
            for (int e = 0; e < 4; ++e) {
                av[e]     = f2bf(a0[e]);
                av[e + 4] = f2bf(a1[e]);
                bv[e]     = f2bf(b0[e]);
                bv[e + 4] = f2bf(b1[e]);
            }
            int boff = row * 128 + ((kc * 16) ^ ((row & 7) << 4));
            *(bf16x8*)((char*)As + boff) = av;
            *(bf16x8*)((char*)Bs + boff) = bv;
        }
        __syncthreads();

        #pragma unroll
        for (int kk = 0; kk < 2; ++kk) {
            bf16x8 a[4], bb[4];
            #pragma unroll
            for (int m = 0; m < 4; ++m) {
                int rr = wr * 64 + m * 16 + lrow;
                int off = rr * 128 + ((kk * 64 + kgrp * 16) ^ ((rr & 7) << 4));
                a[m] = *(const bf16x8*)((const char*)As + off);
            }
            #pragma unroll
            for (int n = 0; n < 4; ++n) {
                int cc = wc * 64 + n * 16 + lrow;
                int off = cc * 128 + ((kk * 64 + kgrp * 16) ^ ((cc & 7) << 4));
                bb[n] = *(const bf16x8*)((const char*)Bs + off);
            }
            #pragma unroll
            for (int m = 0; m < 4; ++m)
                #pragma unroll
                for (int n = 0; n < 4; ++n)
                    acc[m][n] = __builtin_amdgcn_mfma_f32_16x16x32_bf16(
                        a[m], bb[n], acc[m][n], 0, 0, 0);
        }
    }

    float s0 = 0.f, s1 = 0.f, ps = 0.f, pc = 0.f;
    #pragma unroll
    for (int m = 0; m < 4; ++m) {
        #pragma unroll
        for (int e = 0; e < 4; ++e) {
            int li = wr * 64 + m * 16 + kgrp * 4 + e;
            int gi = rowbase + li;
            int labi = lab_r[li];
            int bi   = bia_r[li];
            #pragma unroll
            for (int n = 0; n < 4; ++n) {
                int lj = wc * 64 + n * 16 + lrow;
                int gj = colbase + lj;
                if (gi > gj) {
                    float g = acc[m][n][e];
                    g = fminf(fmaxf(g, -1.f), 1.f);
                    int bj = bia_c[lj];
                    if (bi == bj) {
                        if (bi == 0) s0 += g; else s1 += g;
                    } else if (labi == lab_c[lj] && bi < bj) {
                        ps += 1.f + g;
                        pc += 1.f;
                    }
                }
            }
        }
    }
    #pragma unroll
    for (int off = 32; off > 0; off >>= 1) {
        s0 += __shfl_down(s0, off);
        s1 += __shfl_down(s1, off);
        ps += __shfl_down(ps, off);
        pc += __shfl_down(pc, off);
    }
    if (lane == 0) {
        atomicAdd(&accbuf[0], s0);
        atomicAdd(&accbuf[1], s1);
        atomicAdd(&accbuf[2], ps);
        atomicAdd(&accbuf[3], pc);
    }
}

// ---------------------------------------------------------------------------
// Cross-entropy + bias-class counts.  accbuf: [4]=CE sum [5]=n0 [6]=n1
// ---------------------------------------------------------------------------
__global__ __launch_bounds__(256)
void ce_count_kernel(const float* __restrict__ logits,
                     const int* __restrict__ labels,
                     const int* __restrict__ biases,
                     float* __restrict__ accbuf,
                     int N, int C)
{
    int i = blockIdx.x * blockDim.x + threadIdx.x;
    float loss = 0.f, c0 = 0.f, c1 = 0.f;
    if (i < N) {
        const float* row = logits + (size_t)i * C;
        float mx = -INFINITY;
        for (int k = 0; k < C; ++k) mx = fmaxf(mx, row[k]);
        float s = 0.f;
        for (int k = 0; k < C; ++k) s += expf(row[k] - mx);
        loss = mx + logf(s) - row[labels[i]];
        if (biases[i] == 0) c0 = 1.f; else c1 = 1.f;
    }
    #pragma unroll
    for (int off = 32; off > 0; off >>= 1) {
        loss += __shfl_down(loss, off);
        c0   += __shfl_down(c0, off);
        c1   += __shfl_down(c1, off);
    }
    if ((threadIdx.x & 63) == 0) {
        atomicAdd(&accbuf[4], loss);
        atomicAdd(&accbuf[5], c0);
        atomicAdd(&accbuf[6], c1);
    }
}

// ---------------------------------------------------------------------------
// Finalize
// ---------------------------------------------------------------------------
__global__ void finalize_kernel(const float* __restrict__ accbuf,
                                float* __restrict__ out, int N)
{
    float S0 = accbuf[0], S1 = accbuf[1], ps = accbuf[2], pc = accbuf[3];
    float ce = accbuf[4], n0 = accbuf[5], n1 = accbuf[6];
    float Mo = 0.5f * (n0 * (n0 - 1.f) + n1 * (n1 - 1.f));
    float Ro = (Mo > 0.f) ? (fabsf(S0) + fabsf(S1)) / Mo : 0.f;
    float Rp = (pc > 0.f) ? 1.f + (-0.5f * ps) / pc : 0.f;
    out[0] = ce / (float)N;
    out[1] = Ro + Rp;   // ALPHA=BETA=1
}

extern "C" void kernel_launch(void* const* d_in, const int* in_sizes, int n_in,
                              void* d_out, int out_size, void* d_ws, size_t ws_size,
                              hipStream_t stream)
{
    const float* logits = (const float*)d_in[0];
    const int*   labels = (const int*)d_in[1];
    const int*   biases = (const int*)d_in[2];
    const float* feats  = (const float*)d_in[3];

    int N = in_sizes[1];              // 4096
    int C = in_sizes[0] / N;          // 10
    int D = in_sizes[3] / N;          // 2048

    float* accbuf = (float*)d_ws;
    hipMemsetAsync(accbuf, 0, 8 * sizeof(float), stream);

    size_t need = 256 + (size_t)N * D * sizeof(ushort_t);   // 16 MB + hdr
    if (ws_size >= need && (N & 255) == 0 && (D & 127) == 0) {
        ushort_t* fb = (ushort_t*)((char*)d_ws + 256);
        int nconv = N * D;
        convert_kernel<<<(nconv / 8 + 255) / 256, 256, 0, stream>>>(feats, fb,
                                                                    nconv);
        int nt = N >> 8;              // 16
        gram_8phase_kernel<<<nt * nt, 512, 0, stream>>>(fb, labels, biases,
                                                        accbuf, N, D);
    } else {
        int nt = N / 128;
        int T  = nt * (nt + 1) / 2;
        gram_fused_kernel<<<T, 256, 0, stream>>>(feats, labels, biases, accbuf,
                                                 N, D);
    }
    ce_count_kernel<<<(N + 255) / 256, 256, 0, stream>>>(logits, labels, biases,
                                                         accbuf, N, C);
    finalize_kernel<<<1, 1, 0, stream>>>(accbuf, (float*)d_out, N);
}

// Round 13
// 141.837 us; speedup vs baseline: 1.3345x; 1.0392x over previous
//
#include <hip/hip_runtime.h>
#include <hip/hip_bf16.h>

// Types
typedef short  bf16x8 __attribute__((ext_vector_type(8)));
typedef float  f32x4  __attribute__((ext_vector_type(4)));
typedef unsigned int uint2v __attribute__((ext_vector_type(2)));
typedef unsigned short ushort_t;

#define GLD_LDS16(gp, lp) __builtin_amdgcn_global_load_lds(                 \
    (const __attribute__((address_space(1))) void*)(gp),                    \
    (__attribute__((address_space(3))) void*)(lp), 16, 0, 0)

static __device__ inline short f2bf(float x) {
    unsigned u = __builtin_bit_cast(unsigned, x);
    u += 0x7fffu + ((u >> 16) & 1u);
    return (short)(u >> 16);
}

// ---------------------------------------------------------------------------
// Pre-pass: feats f32 -> fp8 e4m3 with the LDS XOR-swizzle BAKED IN.
// fb[row][kt*64 + p*8 .. +8) = fp8 of feats[row][kt*64 + frag_off(p^(row&7))]
// where frag_off(f) = (f>>2)*32 + (f&3)*8.  Staging then copies fb linearly
// (global_load_lds, perfectly coalesced) and the LDS image is exactly the
// swizzled layout the ds_read side expects (rule #21 both-sides involution).
// ---------------------------------------------------------------------------
__global__ __launch_bounds__(256)
void convert_swz8_kernel(const float* __restrict__ in,
                         unsigned char* __restrict__ out,
                         int N, int D)
{
    int uid = blockIdx.x * blockDim.x + threadIdx.x;   // 8B unit id
    int nw  = D >> 3;                                  // units per row
    if (uid >= N * nw) return;
    int row = uid / nw;
    int w   = uid - row * nw;
    int kt  = w >> 3;                                  // 64-K tile in row
    int p   = w & 7;                                   // unit slot in tile
    int f   = p ^ (row & 7);                           // baked swizzle
    int k   = kt * 64 + ((f >> 2) << 5) + ((f & 3) << 3);
    const float* s = in + (size_t)row * D + k;
    f32x4 a = *(const f32x4*)s;
    f32x4 b = *(const f32x4*)(s + 4);
    unsigned lo = __builtin_amdgcn_cvt_pk_fp8_f32(a[0], a[1], 0, 0);
    lo = __builtin_amdgcn_cvt_pk_fp8_f32(a[2], a[3], lo, 1);
    unsigned hi = __builtin_amdgcn_cvt_pk_fp8_f32(b[0], b[1], 0, 0);
    hi = __builtin_amdgcn_cvt_pk_fp8_f32(b[2], b[3], hi, 1);
    uint2v v = {lo, hi};
    *(uint2v*)(out + (size_t)uid * 8) = v;
}

// ---------------------------------------------------------------------------
// Gram kernel: R12's verified 8-phase 256x256 schedule, fp8 payload.
// 512 threads (8 waves 2Mx4N), BK=64, 2 K-tiles/iter, double-buffered 64KB
// LDS, counted vmcnt(3) at phases 4/8 only (3 half-tiles in flight), raw
// s_barrier + lgkmcnt(0) + setprio(1) around MFMA. Full-square 256 blocks
// (1/CU), XCD swizzle. STAGE = 1 global_load_lds per thread (8KB half-tile).
// accbuf: [0]=S0 [1]=S1 [2]=ps [3]=pc
// ---------------------------------------------------------------------------
__global__ __launch_bounds__(512, 2)
void gram_8phase8_kernel(const unsigned char* __restrict__ fb,
                         const int* __restrict__ labels,
                         const int* __restrict__ biases,
                         float* __restrict__ accbuf,
                         int N, int D)
{
    __shared__ unsigned char As[2][2][128][64];   // [dbuf][half][row][k] 32KB
    __shared__ unsigned char Bs[2][2][128][64];   // 32KB
    __shared__ int lab_r[256], bia_r[256], lab_c[256], bia_c[256];

    int nt = N >> 8;                   // 16
    int b  = blockIdx.x;
    int nwg = gridDim.x;
    if ((nwg & 7) == 0) b = (b & 7) * (nwg >> 3) + (b >> 3);
    int r = b / nt, c = b % nt;
    int rowbase = r * 256, colbase = c * 256;

    int tid = threadIdx.x;
    if (tid < 256) {
        lab_r[tid] = labels[rowbase + tid];
        bia_r[tid] = biases[rowbase + tid];
    } else {
        int u = tid - 256;
        lab_c[u] = labels[colbase + u];
        bia_c[u] = biases[colbase + u];
    }

    int lane = tid & 63;
    int wid  = tid >> 6;               // 8 waves
    int wr   = wid >> 2;               // 0..1  (128 rows each)
    int wc   = wid & 3;                // 0..3  (64 cols each)
    int lrow = lane & 15;
    int kgrp = lane >> 4;

    // stage one half-tile (128 rows x 64 fp8 = 8KB): 512 x 16B, 1/thread.
    // fb already holds the swizzled LDS image -> linear copy.
    auto STAGE_A = [&](int buf, int h, int kt) {
        int row = tid >> 2;
        int blk = tid & 3;
        const unsigned char* g =
            fb + (size_t)(rowbase + h * 128 + row) * D + kt * 64 + blk * 16;
        GLD_LDS16(g, &As[buf][h][0][0] + tid * 16);
    };
    auto STAGE_B = [&](int buf, int h, int kt) {
        int row = tid >> 2;
        int blk = tid & 3;
        const unsigned char* g =
            fb + (size_t)(colbase + h * 128 + row) * D + kt * 64 + blk * 16;
        GLD_LDS16(g, &Bs[buf][h][0][0] + tid * 16);
    };

    f32x4 acc[8][4] = {};
    int nIter = D >> 7;                // 16 iterations, 2 K-tiles each

    // ---- prologue: stage buf0 (K-tiles 0,1), drain once ----
    STAGE_A(0, 0, 0); STAGE_A(0, 1, 0); STAGE_B(0, 0, 0); STAGE_B(0, 1, 0);
    STAGE_A(0, 0, 1); STAGE_A(0, 1, 1); STAGE_B(0, 0, 1); STAGE_B(0, 1, 1);
    asm volatile("s_waitcnt vmcnt(0)" ::: "memory");
    __builtin_amdgcn_s_barrier();

    int hb  = wc >> 1;                 // B half this wave reads
    int lcb = (wc & 1) * 64;           // B local col base within half

    for (int i = 0; i < nIter; ++i) {
        int cur = i & 1;
        int stg = (i + 1 < nIter);
        unsigned long breg[4][2];

        #pragma unroll
        for (int half = 0; half < 2; ++half) {      // K-tile 2i+half
            int ktn = 2 * (i + 1) + half;           // staged K-tile
            #pragma unroll
            for (int q = 0; q < 4; ++q) {           // phase
                // ---- ds_read subtile (b64 fragments, XOR-swizzled) ----
                if (q == 0) {
                    #pragma unroll
                    for (int n = 0; n < 4; ++n)
                        #pragma unroll
                        for (int ks = 0; ks < 2; ++ks) {
                            int lc = lcb + n * 16 + lrow;
                            int u  = (ks * 4 + kgrp) ^ (lc & 7);
                            breg[n][ks] = *(const unsigned long*)(
                                &Bs[cur][hb][lc][0] + u * 8);
                        }
                }
                unsigned long areg[2][2];
                #pragma unroll
                for (int mm = 0; mm < 2; ++mm)
                    #pragma unroll
                    for (int ks = 0; ks < 2; ++ks) {
                        int lr = (q * 2 + mm) * 16 + lrow;
                        int u  = (ks * 4 + kgrp) ^ (lr & 7);
                        areg[mm][ks] = *(const unsigned long*)(
                            &As[cur][wr][lr][0] + u * 8);
                    }
                // ---- stage one half-tile of next iteration ----
                if (stg) {
                    if (q == 0)      STAGE_A(cur ^ 1, 0, ktn);
                    else if (q == 1) STAGE_A(cur ^ 1, 1, ktn);
                    else if (q == 2) STAGE_B(cur ^ 1, 0, ktn);
                    else             STAGE_B(cur ^ 1, 1, ktn);
                }
                // ---- counted vmcnt once per K-tile (3 half-tiles deep) ----
                if (q == 3)
                    asm volatile("s_waitcnt vmcnt(3)" ::: "memory");
                __builtin_amdgcn_s_barrier();
                asm volatile("s_waitcnt lgkmcnt(0)" ::: "memory");
                __builtin_amdgcn_s_setprio(1);
                #pragma unroll
                for (int mm = 0; mm < 2; ++mm)
                    #pragma unroll
                    for (int n = 0; n < 4; ++n)
                        #pragma unroll
                        for (int ks = 0; ks < 2; ++ks)
                            acc[q * 2 + mm][n] =
                                __builtin_amdgcn_mfma_f32_16x16x32_fp8_fp8(
                                    (long)areg[mm][ks], (long)breg[n][ks],
                                    acc[q * 2 + mm][n], 0, 0, 0);
                __builtin_amdgcn_s_setprio(0);
                __builtin_amdgcn_s_barrier();
            }
        }
    }

    if (r < c) return;                 // strictly-upper: no i>j pairs

    // ---- epilogue: clip + masks + reduce (verified R2-R12) ----
    // C/D layout: col = lane&15, row = (lane>>4)*4 + reg
    float s0 = 0.f, s1 = 0.f, ps = 0.f, pc = 0.f;
    #pragma unroll
    for (int m = 0; m < 8; ++m) {
        #pragma unroll
        for (int e = 0; e < 4; ++e) {
            int li = wr * 128 + m * 16 + kgrp * 4 + e;
            int gi = rowbase + li;
            int labi = lab_r[li];
            int bi   = bia_r[li];
            #pragma unroll
            for (int n = 0; n < 4; ++n) {
                int lj = wc * 64 + n * 16 + lrow;
                int gj = colbase + lj;
                if (gi > gj) {
                    float g = acc[m][n][e];
                    g = fminf(fmaxf(g, -1.f), 1.f);
                    int bj = bia_c[lj];
                    if (bi == bj) {
                        if (bi == 0) s0 += g; else s1 += g;
                    } else if (labi == lab_c[lj] && bi < bj) {
                        ps += 1.f + g;
                        pc += 1.f;
                    }
                }
            }
        }
    }
    #pragma unroll
    for (int off = 32; off > 0; off >>= 1) {
        s0 += __shfl_down(s0, off);
        s1 += __shfl_down(s1, off);
        ps += __shfl_down(ps, off);
        pc += __shfl_down(pc, off);
    }
    if (lane == 0) {
        atomicAdd(&accbuf[0], s0);
        atomicAdd(&accbuf[1], s1);
        atomicAdd(&accbuf[2], ps);
        atomicAdd(&accbuf[3], pc);
    }
}

// ---------------------------------------------------------------------------
// Fallback (non-conforming shapes / small ws): fused f32->bf16 (R2, proven)
// ---------------------------------------------------------------------------
__global__ __launch_bounds__(256, 2)
void gram_fused_kernel(const float* __restrict__ feats,
                       const int* __restrict__ labels,
                       const int* __restrict__ biases,
                       float* __restrict__ accbuf,
                       int N, int D)
{
    __shared__ ushort_t As[128 * 64];
    __shared__ ushort_t Bs[128 * 64];
    __shared__ int lab_r[128], bia_r[128], lab_c[128], bia_c[128];

    int t = blockIdx.x;
    int r = (int)((sqrtf(8.0f * (float)t + 1.0f) - 1.0f) * 0.5f);
    while ((r + 1) * (r + 2) / 2 <= t) ++r;
    while (r * (r + 1) / 2 > t) --r;
    int c = t - r * (r + 1) / 2;
    int rowbase = r * 128, colbase = c * 128;

    int tid = threadIdx.x;
    if (tid < 128) {
        lab_r[tid] = labels[rowbase + tid];
        bia_r[tid] = biases[rowbase + tid];
    } else {
        int u = tid - 128;
        lab_c[u] = labels[colbase + u];
        bia_c[u] = biases[colbase + u];
    }

    int lane = tid & 63;
    int wid  = tid >> 6;
    int wr   = wid >> 1;
    int wc   = wid & 1;
    int lrow = lane & 15;
    int kgrp = lane >> 4;

    f32x4 acc[4][4] = {};

    for (int k0 = 0; k0 < D; k0 += 64) {
        __syncthreads();
        #pragma unroll
        for (int it = 0; it < 4; ++it) {
            int wlin = tid + it * 256;
            int row  = wlin >> 3;
            int kc   = wlin & 7;
            const float* ga = feats + (size_t)(rowbase + row) * D + k0 + kc * 8;
            const float* gb = feats + (size_t)(colbase + row) * D + k0 + kc * 8;
            f32x4 a0 = *(const f32x4*)ga;
            f32x4 a1 = *(const f32x4*)(ga + 4);
            f32x4 b0 = *(const f32x4*)gb;
            f32x4 b1 = *(const f32x4*)(gb + 4);
            bf16x8 av, bv;
            #pragma unroll
            for (int e = 0; e < 4; ++e) {
                av[e]     = f2bf(a0[e]);
                av[e + 4] = f2bf(a1[e]);
                bv[e]     = f2bf(b0[e]);
                bv[e + 4] = f2bf(b1[e]);
            }
            int boff = row * 128 + ((kc * 16) ^ ((row & 7) << 4));
            *(bf16x8*)((char*)As + boff) = av;
            *(bf16x8*)((char*)Bs + boff) = bv;
        }
        __syncthreads();

        #pragma unroll
        for (int kk = 0; kk < 2; ++kk) {
            bf16x8 a[4], bb[4];
            #pragma unroll
            for (int m = 0; m < 4; ++m) {
                int rr = wr * 64 + m * 16 + lrow;
                int off = rr * 128 + ((kk * 64 + kgrp * 16) ^ ((rr & 7) << 4));
                a[m] = *(const bf16x8*)((const char*)As + off);
            }
            #pragma unroll
            for (int n = 0; n < 4; ++n) {
                int cc = wc * 64 + n * 16 + lrow;
                int off = cc * 128 + ((kk * 64 + kgrp * 16) ^ ((cc & 7) << 4));
                bb[n] = *(const bf16x8*)((const char*)Bs + off);
            }
            #pragma unroll
            for (int m = 0; m < 4; ++m)
                #pragma unroll
                for (int n = 0; n < 4; ++n)
                    acc[m][n] = __builtin_amdgcn_mfma_f32_16x16x32_bf16(
                        a[m], bb[n], acc[m][n], 0, 0, 0);
        }
    }

    float s0 = 0.f, s1 = 0.f, ps = 0.f, pc = 0.f;
    #pragma unroll
    for (int m = 0; m < 4; ++m) {
        #pragma unroll
        for (int e = 0; e < 4; ++e) {
            int li = wr * 64 + m * 16 + kgrp * 4 + e;
            int gi = rowbase + li;
            int labi = lab_r[li];
            int bi   = bia_r[li];
            #pragma unroll
            for (int n = 0; n < 4; ++n) {
                int lj = wc * 64 + n * 16 + lrow;
                int gj = colbase + lj;
                if (gi > gj) {
                    float g = acc[m][n][e];
                    g = fminf(fmaxf(g, -1.f), 1.f);
                    int bj = bia_c[lj];
                    if (bi == bj) {
                        if (bi == 0) s0 += g; else s1 += g;
                    } else if (labi == lab_c[lj] && bi < bj) {
                        ps += 1.f + g;
                        pc += 1.f;
                    }
                }
            }
        }
    }
    #pragma unroll
    for (int off = 32; off > 0; off >>= 1) {
        s0 += __shfl_down(s0, off);
        s1 += __shfl_down(s1, off);
        ps += __shfl_down(ps, off);
        pc += __shfl_down(pc, off);
    }
    if (lane == 0) {
        atomicAdd(&accbuf[0], s0);
        atomicAdd(&accbuf[1], s1);
        atomicAdd(&accbuf[2], ps);
        atomicAdd(&accbuf[3], pc);
    }
}

// ---------------------------------------------------------------------------
// Cross-entropy + bias-class counts.  accbuf: [4]=CE sum [5]=n0 [6]=n1
// ---------------------------------------------------------------------------
__global__ __launch_bounds__(256)
void ce_count_kernel(const float* __restrict__ logits,
                     const int* __restrict__ labels,
                     const int* __restrict__ biases,
                     float* __restrict__ accbuf,
                     int N, int C)
{
    int i = blockIdx.x * blockDim.x + threadIdx.x;
    float loss = 0.f, c0 = 0.f, c1 = 0.f;
    if (i < N) {
        const float* row = logits + (size_t)i * C;
        float mx = -INFINITY;
        for (int k = 0; k < C; ++k) mx = fmaxf(mx, row[k]);
        float s = 0.f;
        for (int k = 0; k < C; ++k) s += expf(row[k] - mx);
        loss = mx + logf(s) - row[labels[i]];
        if (biases[i] == 0) c0 = 1.f; else c1 = 1.f;
    }
    #pragma unroll
    for (int off = 32; off > 0; off >>= 1) {
        loss += __shfl_down(loss, off);
        c0   += __shfl_down(c0, off);
        c1   += __shfl_down(c1, off);
    }
    if ((threadIdx.x & 63) == 0) {
        atomicAdd(&accbuf[4], loss);
        atomicAdd(&accbuf[5], c0);
        atomicAdd(&accbuf[6], c1);
    }
}

// ---------------------------------------------------------------------------
// Finalize
// ---------------------------------------------------------------------------
__global__ void finalize_kernel(const float* __restrict__ accbuf,
                                float* __restrict__ out, int N)
{
    float S0 = accbuf[0], S1 = accbuf[1], ps = accbuf[2], pc = accbuf[3];
    float ce = accbuf[4], n0 = accbuf[5], n1 = accbuf[6];
    float Mo = 0.5f * (n0 * (n0 - 1.f) + n1 * (n1 - 1.f));
    float Ro = (Mo > 0.f) ? (fabsf(S0) + fabsf(S1)) / Mo : 0.f;
    float Rp = (pc > 0.f) ? 1.f + (-0.5f * ps) / pc : 0.f;
    out[0] = ce / (float)N;
    out[1] = Ro + Rp;   // ALPHA=BETA=1
}

extern "C" void kernel_launch(void* const* d_in, const int* in_sizes, int n_in,
                              void* d_out, int out_size, void* d_ws, size_t ws_size,
                              hipStream_t stream)
{
    const float* logits = (const float*)d_in[0];
    const int*   labels = (const int*)d_in[1];
    const int*   biases = (const int*)d_in[2];
    const float* feats  = (const float*)d_in[3];

    int N = in_sizes[1];              // 4096
    int C = in_sizes[0] / N;          // 10
    int D = in_sizes[3] / N;          // 2048

    float* accbuf = (float*)d_ws;
    hipMemsetAsync(accbuf, 0, 8 * sizeof(float), stream);

    size_t need = 256 + (size_t)N * D;           // 8 MB fp8 + hdr
    if (ws_size >= need && (N & 255) == 0 && (D & 127) == 0) {
        unsigned char* fb = (unsigned char*)d_ws + 256;
        int nu = N * (D >> 3);
        convert_swz8_kernel<<<(nu + 255) / 256, 256, 0, stream>>>(feats, fb,
                                                                  N, D);
        int nt = N >> 8;              // 16
        gram_8phase8_kernel<<<nt * nt, 512, 0, stream>>>(fb, labels, biases,
                                                         accbuf, N, D);
    } else {
        int nt = N / 128;
        int T  = nt * (nt + 1) / 2;
        gram_fused_kernel<<<T, 256, 0, stream>>>(feats, labels, biases, accbuf,
                                                 N, D);
    }
    ce_count_kernel<<<(N + 255) / 256, 256, 0, stream>>>(logits, labels, biases,
                                                         accbuf, N, C);
    finalize_kernel<<<1, 1, 0, stream>>>(accbuf, (float*)d_out, N);
}